// Round 3
// baseline (287.957 us; speedup 1.0000x reference)
//
#include <hip/hip_runtime.h>

#define DIM        512
#define B_POS      1024
#define N_NEG      8192
#define N_RULES    20
#define NEG_RATIO  8

#define NEG_BLKS   2048          // 4 waves/block * 2048 = 8192 neg waves
#define RULE_BLKS  256           // 4 waves/block * 256  = 1024 rule waves
#define NBLK_WORK  (NEG_BLKS + RULE_BLKS)   // 2304 worker blocks
#define MARKER     0x1F2E3D4C

__device__ __forceinline__ float wave_sum(float x) {
#pragma unroll
    for (int off = 32; off > 0; off >>= 1)
        x += __shfl_xor(x, off, 64);
    return x;
}

// ||proj(h) + r - proj(t)||, w unnormalized:
// d = he - te;  v = d + re - ((d.w)/(w.w)) * w;  return ||v||
__device__ __forceinline__ float transh_dist(
    int h, int r, int t,
    const float* __restrict__ ent, const float* __restrict__ rel,
    const float* __restrict__ nv, int lane)
{
    const float4* wp = (const float4*)(nv  + (size_t)r * DIM);
    const float4* hp = (const float4*)(ent + (size_t)h * DIM);
    const float4* tp = (const float4*)(ent + (size_t)t * DIM);
    const float4* rp = (const float4*)(rel + (size_t)r * DIM);

    float4 wv[2], dv[2], rv[2];
    float ww = 0.f, dw = 0.f;
#pragma unroll
    for (int c = 0; c < 2; ++c) {
        float4 w  = wp[lane + 64 * c];
        float4 hh = hp[lane + 64 * c];
        float4 tt = tp[lane + 64 * c];
        float4 rr = rp[lane + 64 * c];
        float4 d;
        d.x = hh.x - tt.x; d.y = hh.y - tt.y; d.z = hh.z - tt.z; d.w = hh.w - tt.w;
        wv[c] = w; dv[c] = d; rv[c] = rr;
        ww += w.x * w.x + w.y * w.y + w.z * w.z + w.w * w.w;
        dw += d.x * w.x + d.y * w.y + d.z * w.z + d.w * w.w;
    }
    ww = wave_sum(ww);
    dw = wave_sum(dw);
    float s = dw / ww;

    float ss = 0.f;
#pragma unroll
    for (int c = 0; c < 2; ++c) {
        float vx = dv[c].x + rv[c].x - s * wv[c].x;
        float vy = dv[c].y + rv[c].y - s * wv[c].y;
        float vz = dv[c].z + rv[c].z - s * wv[c].z;
        float vw = dv[c].w + rv[c].w - s * wv[c].w;
        ss += vx * vx + vy * vy + vz * vz + vw * vw;
    }
    ss = wave_sum(ss);
    return sqrtf(ss);
}

// Single launch. Blocks 0..2047: one wave per negative (dp recomputed, depth-2
// chain). Blocks 2048..2303: one wave per pos triple, rule loop (~41 dists
// grid-wide). Block 2304: spin-waits on ready flags (poison 0xAA.. != MARKER,
// so no zero-init), then reduces the 2304 partials and writes out.
__global__ __launch_bounds__(256) void fused_kernel(
    const int* __restrict__ pos, const int* __restrict__ neg,
    const int* __restrict__ rule_r1, const int* __restrict__ rule_r2,
    const float* __restrict__ rule_conf,
    const float* __restrict__ ent, const float* __restrict__ rel,
    const float* __restrict__ nv,
    float* __restrict__ partial, int* __restrict__ flags,
    float* __restrict__ out)
{
    int b = blockIdx.x;

    if (b == NBLK_WORK) {                       // ---- reducer block ----
        int t = threadIdx.x;
#pragma unroll
        for (int m = 0; m < NBLK_WORK / 256; ++m) {   // 9 flags per thread
            int idx = t + 256 * m;
            while (__hip_atomic_load(&flags[idx], __ATOMIC_ACQUIRE,
                                     __HIP_MEMORY_SCOPE_AGENT) != MARKER) { }
        }
        float s = 0.f;
#pragma unroll
        for (int m = 0; m < NBLK_WORK / 256; ++m)
            s += partial[t + 256 * m];
        s = wave_sum(s);
        __shared__ float part[4];
        int w = t >> 6, lane = t & 63;
        if (lane == 0) part[w] = s;
        __syncthreads();
        if (t == 0) out[0] = part[0] + part[1] + part[2] + part[3];
        return;
    }

    int w    = threadIdx.x >> 6;
    int lane = threadIdx.x & 63;
    float contrib = 0.f;

    if (b < NEG_BLKS) {                         // ---- negative waves ----
        int n = b * 4 + w;                      // neg index 0..8191
        int i = n >> 3;                         // matching pos index
        float dp = transh_dist(pos[3 * i], pos[3 * i + 1], pos[3 * i + 2],
                               ent, rel, nv, lane);
        float dn = transh_dist(neg[3 * n], neg[3 * n + 1], neg[3 * n + 2],
                               ent, rel, nv, lane);
        float v = 1.0f + dp - dn;
        contrib = ((v > 0.f) ? v : 0.f) * (1.0f / (float)N_NEG);
    } else {                                    // ---- rule waves ----
        int i = (b - NEG_BLKS) * 4 + w;         // pos index 0..1023
        int h = pos[3 * i], r = pos[3 * i + 1], t = pos[3 * i + 2];
        float racc = 0.f;
        for (int j = 0; j < N_RULES; ++j) {
            if (r == rule_r1[j]) {
                float d = transh_dist(h, rule_r2[j], t, ent, rel, nv, lane);
                racc += rule_conf[j] * d;
            }
        }
        contrib = 0.5f * racc;
    }

    __shared__ float part[4];
    if (lane == 0) part[w] = contrib;
    __syncthreads();
    if (threadIdx.x == 0) {
        partial[b] = part[0] + part[1] + part[2] + part[3];
        __hip_atomic_store(&flags[b], MARKER, __ATOMIC_RELEASE,
                           __HIP_MEMORY_SCOPE_AGENT);
    }
}

extern "C" void kernel_launch(void* const* d_in, const int* in_sizes, int n_in,
                              void* d_out, int out_size, void* d_ws, size_t ws_size,
                              hipStream_t stream) {
    const int*   pos       = (const int*)  d_in[0];
    const int*   neg       = (const int*)  d_in[1];
    const int*   rule_r1   = (const int*)  d_in[2];
    const int*   rule_r2   = (const int*)  d_in[3];
    const float* rule_conf = (const float*)d_in[4];
    const float* ent       = (const float*)d_in[5];
    const float* rel       = (const float*)d_in[6];
    const float* nv        = (const float*)d_in[7];
    float* out = (float*)d_out;

    float* partial = (float*)d_ws;              // NBLK_WORK floats
    int*   flags   = (int*)(partial + NBLK_WORK);

    fused_kernel<<<NBLK_WORK + 1, 256, 0, stream>>>(
        pos, neg, rule_r1, rule_r2, rule_conf, ent, rel, nv,
        partial, flags, out);
}

// Round 4
// 251.185 us; speedup vs baseline: 1.1464x; 1.1464x over previous
//
#include <hip/hip_runtime.h>

#define DIM        512
#define B_POS      1024
#define N_NEG      8192
#define N_RULES    20
#define NEG_RATIO  8
#define NBLK       2048   // 4 waves/block * 2048 = 8192 waves = 1 per negative

__device__ __forceinline__ float wave_sum(float x) {
#pragma unroll
    for (int off = 32; off > 0; off >>= 1)
        x += __shfl_xor(x, off, 64);
    return x;
}

// ||proj(h) + r - proj(t)||, w unnormalized:
// d = he - te;  v = d + re - ((d.w)/(w.w)) * w;  return ||v||
__device__ __forceinline__ float transh_dist(
    int h, int r, int t,
    const float* __restrict__ ent, const float* __restrict__ rel,
    const float* __restrict__ nv, int lane)
{
    const float4* wp = (const float4*)(nv  + (size_t)r * DIM);
    const float4* hp = (const float4*)(ent + (size_t)h * DIM);
    const float4* tp = (const float4*)(ent + (size_t)t * DIM);
    const float4* rp = (const float4*)(rel + (size_t)r * DIM);

    float4 wv[2], dv[2], rv[2];
    float ww = 0.f, dw = 0.f;
#pragma unroll
    for (int c = 0; c < 2; ++c) {
        float4 w  = wp[lane + 64 * c];
        float4 hh = hp[lane + 64 * c];
        float4 tt = tp[lane + 64 * c];
        float4 rr = rp[lane + 64 * c];
        float4 d;
        d.x = hh.x - tt.x; d.y = hh.y - tt.y; d.z = hh.z - tt.z; d.w = hh.w - tt.w;
        wv[c] = w; dv[c] = d; rv[c] = rr;
        ww += w.x * w.x + w.y * w.y + w.z * w.z + w.w * w.w;
        dw += d.x * w.x + d.y * w.y + d.z * w.z + d.w * w.w;
    }
    ww = wave_sum(ww);
    dw = wave_sum(dw);
    float s = dw / ww;

    float ss = 0.f;
#pragma unroll
    for (int c = 0; c < 2; ++c) {
        float vx = dv[c].x + rv[c].x - s * wv[c].x;
        float vy = dv[c].y + rv[c].y - s * wv[c].y;
        float vz = dv[c].z + rv[c].z - s * wv[c].z;
        float vw = dv[c].w + rv[c].w - s * wv[c].w;
        ss += vx * vx + vy * vy + vz * vz + vw * vw;
    }
    ss = wave_sum(ss);
    return sqrtf(ss);
}

// One wave per negative n: dp (pos n>>3, recomputed x8 -- latency-parallel),
// dn, plus rule slots {k, k+8, k+16} for k = n&7 (covers all 20 rules exactly
// once per pos triple; ~41 surviving dists grid-wide). Serial depth 2 (+rare
// rule hit) at full residency (2048 blocks = 8/CU, one dispatch round).
__global__ __launch_bounds__(256) void fused_kernel(
    const int* __restrict__ pos, const int* __restrict__ neg,
    const int* __restrict__ rule_r1, const int* __restrict__ rule_r2,
    const float* __restrict__ rule_conf,
    const float* __restrict__ ent, const float* __restrict__ rel,
    const float* __restrict__ nv,
    float* __restrict__ partial)
{
    int w    = threadIdx.x >> 6;
    int lane = threadIdx.x & 63;
    int n    = blockIdx.x * 4 + w;          // negative index 0..8191
    int i    = n >> 3;                      // pos triple index
    int k    = n & 7;                       // rule-slot selector

    int h = pos[3 * i], r = pos[3 * i + 1], t = pos[3 * i + 2];
    float dp = transh_dist(h, r, t, ent, rel, nv, lane);
    float dn = transh_dist(neg[3 * n], neg[3 * n + 1], neg[3 * n + 2],
                           ent, rel, nv, lane);
    float v = 1.0f + dp - dn;
    float contrib = ((v > 0.f) ? v : 0.f) * (1.0f / (float)N_NEG);

    // rule slots: j = k, k+8, k+16 (j < 20)
    float racc = 0.f;
#pragma unroll
    for (int m = 0; m < 3; ++m) {
        int j = k + 8 * m;
        if (j < N_RULES && r == rule_r1[j]) {
            float d = transh_dist(h, rule_r2[j], t, ent, rel, nv, lane);
            racc += rule_conf[j] * d;
        }
    }
    contrib += 0.5f * racc;

    __shared__ float part[4];
    if (lane == 0) part[w] = contrib;
    __syncthreads();
    if (threadIdx.x == 0)
        partial[blockIdx.x] = part[0] + part[1] + part[2] + part[3];
}

__global__ __launch_bounds__(256) void final_reduce(
    const float* __restrict__ partial, float* __restrict__ out)
{
    int t = threadIdx.x;
    float s = 0.f;
#pragma unroll
    for (int m = 0; m < NBLK / 256; ++m)
        s += partial[t + 256 * m];
    s = wave_sum(s);
    __shared__ float part[4];
    int w = t >> 6, lane = t & 63;
    if (lane == 0) part[w] = s;
    __syncthreads();
    if (t == 0) out[0] = part[0] + part[1] + part[2] + part[3];
}

extern "C" void kernel_launch(void* const* d_in, const int* in_sizes, int n_in,
                              void* d_out, int out_size, void* d_ws, size_t ws_size,
                              hipStream_t stream) {
    const int*   pos       = (const int*)  d_in[0];
    const int*   neg       = (const int*)  d_in[1];
    const int*   rule_r1   = (const int*)  d_in[2];
    const int*   rule_r2   = (const int*)  d_in[3];
    const float* rule_conf = (const float*)d_in[4];
    const float* ent       = (const float*)d_in[5];
    const float* rel       = (const float*)d_in[6];
    const float* nv        = (const float*)d_in[7];
    float* out     = (float*)d_out;
    float* partial = (float*)d_ws;   // NBLK floats, every block writes -> no init

    fused_kernel<<<NBLK, 256, 0, stream>>>(pos, neg, rule_r1, rule_r2, rule_conf,
                                           ent, rel, nv, partial);
    final_reduce<<<1, 256, 0, stream>>>(partial, out);
}